// Round 4
// baseline (773.523 us; speedup 1.0000x reference)
//
#include <hip/hip_runtime.h>

#define NS   50000
#define LSEQ 32
#define IND  64
#define HIDN 64
#define OUTD 128
#define NR   11

using bf16x8  = __attribute__((ext_vector_type(8))) short;
using f32x16  = __attribute__((ext_vector_type(16))) float;

union U8 { bf16x8 v; unsigned u[4]; uint2 d[2]; };

__device__ __forceinline__ unsigned cvt_pk_bf16(float a, float b) {
  unsigned r;
  asm volatile("v_cvt_pk_bf16_f32 %0, %1, %2" : "=v"(r) : "v"(a), "v"(b));
  return r;  // r[15:0] = bf16(a), r[31:16] = bf16(b)
}
__device__ __forceinline__ float fsig(float x) {
  return __builtin_amdgcn_rcpf(1.f + __expf(-x));
}
__device__ __forceinline__ float ftanh_(float x) {
  return 1.f - 2.f * __builtin_amdgcn_rcpf(__expf(2.f * x) + 1.f);
}
__device__ __forceinline__ void gload_lds16(const void* g, void* l) {
  __builtin_amdgcn_global_load_lds(
      (const __attribute__((address_space(1))) unsigned*)g,
      (__attribute__((address_space(3))) unsigned*)l, 16, 0, 0);
}

// ---------------- length sort (descending): 32-bin counting sort -----------
__global__ void zero_cnt_kernel(int* cnt) {
  if (threadIdx.x < 64) cnt[threadIdx.x] = 0;  // cnt[32] + cur[32]
}
__global__ void hist_kernel(const int* __restrict__ lens, int* __restrict__ cnt) {
  int s = blockIdx.x * 256 + threadIdx.x;
  if (s < NS) atomicAdd(&cnt[32 - lens[s]], 1);
}
__global__ void prefix_kernel(const int* __restrict__ cnt, int* __restrict__ cur) {
  if (threadIdx.x == 0) {
    int sum = 0;
    for (int b = 0; b < 32; ++b) { cur[b] = sum; sum += cnt[b]; }
  }
}
__global__ void scatter_kernel(const int* __restrict__ lens, int* __restrict__ cur,
                               int* __restrict__ ord) {
  int s = blockIdx.x * 256 + threadIdx.x;
  if (s < NS) {
    int pos = atomicAdd(&cur[32 - lens[s]], 1);
    ord[pos] = s;
  }
}

// ---------------------------------------------------------------------------
// K1: fused gather + bf16-MFMA LSTM + relation pooling, length-sorted blocks.
// 512 thr / 8 waves / 32 samples. Per-block step count = block-max length
// (sorted descending -> sh_len[0]). 2-deep gather prefetch; single barrier
// per step; double-buffered XOR-swizzled activation tile.
// ---------------------------------------------------------------------------
__global__ __launch_bounds__(512, 4) void lstm_mfma_kernel(
    const int* __restrict__ nbr, const int* __restrict__ lens,
    const int* __restrict__ rels, const float* __restrict__ adjw,
    const float* __restrict__ feat, const float* __restrict__ Wih,
    const float* __restrict__ Whh, const int* __restrict__ ord,
    unsigned* __restrict__ phi, unsigned* __restrict__ plo,
    int s0, int cnt)
{
  __shared__ short xh[2 * 32 * 128];   // 16KB: 2 x [32 samp][128 k] bf16, swizzled
  __shared__ float sh_w[32][33];
  __shared__ int   sh_meta[32][33];    // rel<<16 | nbr (nbr < 2^16)
  __shared__ int   sh_len[32];

  const int tid   = threadIdx.x;
  const int lane  = tid & 63;
  const int w     = tid >> 6;
  const int sbase = blockIdx.x * 32;

  for (int i = tid; i < 32 * 32; i += 512) {
    int ss = i >> 5, l = i & 31;
    int gp = sbase + ss;
    bool ok = gp < cnt;
    int gs = ok ? ord[s0 + gp] : 0;
    size_t off = (size_t)gs * LSEQ + l;
    sh_w[ss][l]    = ok ? adjw[off] : 0.f;
    sh_meta[ss][l] = ok ? ((rels[off] << 16) | nbr[off]) : 0;
  }
  if (tid < 32) {
    int gp = sbase + tid;
    sh_len[tid] = (gp < cnt) ? lens[ord[s0 + gp]] : 0;
  }
  for (int i = tid; i < 2 * 32 * 128; i += 512) xh[i] = 0;

  // stationary A fragments (gate-permuted weight rows, bf16)
  bf16x8 Af[8];
  {
    const int rr = lane & 31, kh = lane >> 5;
    const int g = rr & 3, q = rr >> 2;
    const int u = w * 8 + 4 * (q & 1) + (q >> 1);
    const int row = g * 64 + u;
#pragma unroll
    for (int kc = 0; kc < 8; ++kc) {
      int k0 = kc * 16 + kh * 8;
      const float* src = (k0 < 64) ? (Wih + row * 64 + k0)
                                   : (Whh + row * 64 + (k0 - 64));
      float4 f0 = *(const float4*)(src);
      float4 f1 = *(const float4*)(src + 4);
      U8 a;
      a.u[0] = cvt_pk_bf16(f0.x, f0.y); a.u[1] = cvt_pk_bf16(f0.z, f0.w);
      a.u[2] = cvt_pk_bf16(f1.x, f1.y); a.u[3] = cvt_pk_bf16(f1.z, f1.w);
      Af[kc] = a.v;
    }
  }

  const int s    = lane & 31;          // gate-phase sample
  const int hi   = lane >> 5;
  const int sxor = (s & 15) << 4;
  const int u0   = w * 8 + 4 * hi;     // 4 consecutive units
  const int hoff = s * 128 + (((128 + u0 * 2) ^ sxor) >> 1);   // short idx
  const int gsamp = tid >> 4, gseg = tid & 15;                 // gather role
  const int goff  = gsamp * 128 + (((gseg * 8) ^ ((gsamp & 15) << 4)) >> 1);

  float c4[4] = {0.f, 0.f, 0.f, 0.f};
  float pooled[4][NR] = {};

  __syncthreads();
  const int len_s = sh_len[s];
  const int len_g = sh_len[gsamp];
  const int tmax  = (sh_len[0] + 1) & ~1;   // block max (descending sort), even

  {  // prologue: x_0 -> buf0
    float4 xv = make_float4(0.f, 0.f, 0.f, 0.f);
    if (0 < len_g) {
      int nid = sh_meta[gsamp][0] & 0xffff;
      xv = *(const float4*)(feat + (size_t)nid * IND + gseg * 4);
    }
    *(uint2*)&xh[goff] = make_uint2(cvt_pk_bf16(xv.x, xv.y),
                                    cvt_pk_bf16(xv.z, xv.w));
  }
  float4 xA = make_float4(0.f, 0.f, 0.f, 0.f), xB;
  if (1 < len_g) {
    int nid = sh_meta[gsamp][1] & 0xffff;
    xA = *(const float4*)(feat + (size_t)nid * IND + gseg * 4);
  }
  __syncthreads();

#define HALFSTEP(bufR, bufW, XLOAD, XWRITE, tc)                              \
  {                                                                          \
    float4 xn = make_float4(0.f, 0.f, 0.f, 0.f);                             \
    if ((tc) + 2 < len_g) {                                                  \
      int nid = sh_meta[gsamp][(tc) + 2] & 0xffff;                           \
      xn = *(const float4*)(feat + (size_t)nid * IND + gseg * 4);            \
    }                                                                        \
    XLOAD = xn;                                                              \
    f32x16 acc = {};                                                         \
    _Pragma("unroll")                                                        \
    for (int kc = 0; kc < 8; ++kc) {                                         \
      int roff = s * 128 + (((kc * 32 + hi * 16) ^ sxor) >> 1);              \
      bf16x8 b = *(const bf16x8*)(&xh[(bufR) + roff]);                       \
      acc = __builtin_amdgcn_mfma_f32_32x32x16_bf16(Af[kc], b, acc, 0, 0, 0);\
    }                                                                        \
    int pk = sh_meta[s][tc];                                                 \
    float wv = ((tc) < len_s) ? sh_w[s][tc] : 0.f;                           \
    int rl = pk >> 16;                                                       \
    float h4[4];                                                             \
    _Pragma("unroll")                                                        \
    for (int p = 0; p < 4; ++p) {                                            \
      float gi = fsig(acc[4 * p + 0]);                                       \
      float gf = fsig(acc[4 * p + 1]);                                       \
      float gg = ftanh_(acc[4 * p + 2]);                                     \
      float go = fsig(acc[4 * p + 3]);                                       \
      float cc = gf * c4[p] + gi * gg;                                       \
      c4[p] = cc;                                                            \
      h4[p] = go * ftanh_(cc);                                               \
    }                                                                        \
    _Pragma("unroll")                                                        \
    for (int r = 0; r < NR; ++r) {                                           \
      float mr = (rl == r) ? wv : 0.f;                                       \
      pooled[0][r] += mr * h4[0]; pooled[1][r] += mr * h4[1];                \
      pooled[2][r] += mr * h4[2]; pooled[3][r] += mr * h4[3];                \
    }                                                                        \
    *(uint2*)&xh[(bufW) + hoff] = make_uint2(cvt_pk_bf16(h4[0], h4[1]),      \
                                             cvt_pk_bf16(h4[2], h4[3]));     \
    *(uint2*)&xh[(bufW) + goff] = make_uint2(cvt_pk_bf16(XWRITE.x, XWRITE.y),\
                                             cvt_pk_bf16(XWRITE.z, XWRITE.w));\
    __syncthreads();                                                         \
  }

#pragma unroll 1
  for (int t = 0; t < tmax; t += 2) {
    HALFSTEP(0,    4096, xB, xA, t)
    HALFSTEP(4096, 0,    xA, xB, t + 1)
  }
#undef HALFSTEP

  // pooled -> hi/lo bf16 planes: [sorted-pos][11][64] bf16 each
  if (sbase + s < cnt) {
    size_t base = ((size_t)(sbase + s) * NR) * 32;
#pragma unroll
    for (int r = 0; r < NR; ++r) {
      float p0 = pooled[0][r], p1 = pooled[1][r];
      float p2 = pooled[2][r], p3 = pooled[3][r];
      unsigned h0 = cvt_pk_bf16(p0, p1), h1 = cvt_pk_bf16(p2, p3);
      float l0 = p0 - __uint_as_float(h0 << 16);
      float l1 = p1 - __uint_as_float(h0 & 0xffff0000u);
      float l2 = p2 - __uint_as_float(h1 << 16);
      float l3 = p3 - __uint_as_float(h1 & 0xffff0000u);
      unsigned g0 = cvt_pk_bf16(l0, l1), g1 = cvt_pk_bf16(l2, l3);
      *(uint2*)&phi[base + r * 32 + (u0 >> 1)] = make_uint2(h0, h1);
      *(uint2*)&plo[base + r * 32 + (u0 >> 1)] = make_uint2(g0, g1);
    }
  }
}

// ---------------------------------------------------------------------------
// Prep: Wr[11][64][128] f32 -> wt[r]: [hi 16KB | lo 16KB], each [128 o][64 k]
// bf16 with baked 4-bit XOR swizzle (byte ^= (o&15)<<3) for conflict-free b64.
// ---------------------------------------------------------------------------
__global__ __launch_bounds__(256) void wprep_kernel(
    const float* __restrict__ Wr, unsigned* __restrict__ wt)
{
  __shared__ float wl[64 * 128];
  const int r = blockIdx.x;
  for (int i = threadIdx.x; i < 64 * 128; i += 256)
    wl[i] = Wr[r * 64 * 128 + i];
  __syncthreads();
  const int o = threadIdx.x >> 1, kb = (threadIdx.x & 1) * 32;
  const int sw = (o & 15) << 3;
  unsigned* hip = wt + r * 8192;
  unsigned* lop = hip + 4096;
  for (int k = kb; k < kb + 32; k += 2) {
    float f0 = wl[k * 128 + o], f1 = wl[(k + 1) * 128 + o];
    unsigned h = cvt_pk_bf16(f0, f1);
    float l0 = f0 - __uint_as_float(h << 16);
    float l1 = f1 - __uint_as_float(h & 0xffff0000u);
    unsigned l = cvt_pk_bf16(l0, l1);
    int byte = o * 128 + ((k * 2) ^ sw);
    hip[byte >> 2] = h;
    lop[byte >> 2] = l;
  }
}

// ---------------------------------------------------------------------------
// K2: proj = sum_r pooled_r @ W_r via split-bf16 MFMA (hi*hi + hi*lo + lo*hi),
// D[m=out][n=samp]; atomic scatter to out[nodes]. 256 thr / 4 waves / 64 samp.
// ---------------------------------------------------------------------------
__global__ __launch_bounds__(256, 4) void rgc_mfma_kernel(
    const unsigned* __restrict__ wt, const unsigned* __restrict__ phi,
    const unsigned* __restrict__ plo, const int* __restrict__ nodes,
    const int* __restrict__ ord, float* __restrict__ out, int s0, int cnt)
{
  __shared__ short wl[2 * 8192];   // 32KB: W hi | lo tile for current r
  const int tid = threadIdx.x, lane = tid & 63, nt = tid >> 6;
  const int l31 = lane & 31, lhi = lane >> 5;
  const int sbase = blockIdx.x * 64;

  const int row = nt * 32 + l31;            // wT row = out index
  const int rsw = (row & 15) << 3;
  int aoff[8];
#pragma unroll
  for (int kc = 0; kc < 4; ++kc)
#pragma unroll
    for (int hf = 0; hf < 2; ++hf)
      aoff[kc * 2 + hf] = row * 64 + (((kc * 32 + lhi * 16 + hf * 8) ^ rsw) >> 1);

  f32x16 acc0 = {}, acc1 = {};

  for (int r = 0; r < NR; ++r) {
    __syncthreads();
    {
      const char* src = (const char*)(wt + r * 8192);
#pragma unroll
      for (int i = 0; i < 8; ++i) {
        int off = (i * 4 + nt) * 1024 + lane * 16;
        gload_lds16(src + off, (char*)wl + off);
      }
    }
    __syncthreads();

    bf16x8 ahi[4], alo[4];
#pragma unroll
    for (int kc = 0; kc < 4; ++kc) {
      U8 a, b;
      a.d[0] = *(const uint2*)&wl[aoff[kc * 2 + 0]];
      a.d[1] = *(const uint2*)&wl[aoff[kc * 2 + 1]];
      b.d[0] = *(const uint2*)&wl[8192 + aoff[kc * 2 + 0]];
      b.d[1] = *(const uint2*)&wl[8192 + aoff[kc * 2 + 1]];
      ahi[kc] = a.v; alo[kc] = b.v;
    }

#pragma unroll
    for (int st = 0; st < 2; ++st) {
      f32x16& accr = st ? acc1 : acc0;
      int samp = sbase + st * 32 + l31;
      size_t bb = ((size_t)samp * NR + r) * 32 + lhi * 4;
#pragma unroll
      for (int kc = 0; kc < 4; ++kc) {
        U8 bh, bl;
        *(uint4*)bh.u = *(const uint4*)&phi[bb + kc * 8];
        *(uint4*)bl.u = *(const uint4*)&plo[bb + kc * 8];
        accr = __builtin_amdgcn_mfma_f32_32x32x16_bf16(ahi[kc], bh.v, accr, 0, 0, 0);
        accr = __builtin_amdgcn_mfma_f32_32x32x16_bf16(ahi[kc], bl.v, accr, 0, 0, 0);
        accr = __builtin_amdgcn_mfma_f32_32x32x16_bf16(alo[kc], bh.v, accr, 0, 0, 0);
      }
    }
  }

#pragma unroll
  for (int st = 0; st < 2; ++st) {
    int sl = sbase + st * 32 + l31;
    if (sl < cnt) {
      int nd = nodes[ord[s0 + sl]];
      float* dst = out + (size_t)nd * OUTD + nt * 32;
      const f32x16& a = st ? acc1 : acc0;
#pragma unroll
      for (int j = 0; j < 16; ++j) {
        int m = (j & 3) + 8 * (j >> 2) + 4 * lhi;
        atomicAdd(dst + m, a[j]);
      }
    }
  }
}

__global__ void relu_kernel(float4* __restrict__ out, int n4) {
  int i = blockIdx.x * 256 + threadIdx.x;
  if (i < n4) {
    float4 v = out[i];
    v.x = fmaxf(v.x, 0.f); v.y = fmaxf(v.y, 0.f);
    v.z = fmaxf(v.z, 0.f); v.w = fmaxf(v.w, 0.f);
    out[i] = v;
  }
}

extern "C" void kernel_launch(void* const* d_in, const int* in_sizes, int n_in,
                              void* d_out, int out_size, void* d_ws, size_t ws_size,
                              hipStream_t stream) {
  const int*   nbr   = (const int*)d_in[0];
  const int*   lens  = (const int*)d_in[1];
  const int*   rels  = (const int*)d_in[2];
  const int*   nodes = (const int*)d_in[3];
  const float* adjw  = (const float*)d_in[4];
  const float* feat  = (const float*)d_in[5];
  const float* Wih   = (const float*)d_in[6];
  const float* Whh   = (const float*)d_in[7];
  const float* Wr    = (const float*)d_in[8];
  float* out = (float*)d_out;

  hipMemsetAsync(d_out, 0, (size_t)NS * OUTD * sizeof(float), stream);

  // ws layout: wt [0,360448) | ord [360448,560448) | cnt/cur 64 ints | phi/plo
  unsigned* wt  = (unsigned*)d_ws;
  int*      ord = (int*)((char*)d_ws + 360448);
  int*      cnt = (int*)((char*)d_ws + 560448);
  int*      cur = cnt + 32;
  unsigned* phi = (unsigned*)((char*)d_ws + 561152);

  wprep_kernel<<<NR, 256, 0, stream>>>(Wr, wt);
  zero_cnt_kernel<<<1, 64, 0, stream>>>(cnt);
  hist_kernel<<<(NS + 255) / 256, 256, 0, stream>>>(lens, cnt);
  prefix_kernel<<<1, 64, 0, stream>>>(cnt, cur);
  scatter_kernel<<<(NS + 255) / 256, 256, 0, stream>>>(lens, cur, ord);

  size_t avail = (ws_size > 561152) ? ws_size - 561152 : 0;
  long long cap = (long long)(avail / 2816);     // samples (1408B x 2 planes)
  long long ch = cap - 64;
  ch &= ~63LL;
  if (ch > NS) ch = NS;
  if (ch < 64) ch = 64;
  unsigned* plo = phi + (size_t)cap * 352;       // 352 u32 = 1408B per sample

  for (int s0 = 0; s0 < NS; s0 += (int)ch) {
    int cnt_c = (NS - s0 < (int)ch) ? (NS - s0) : (int)ch;
    lstm_mfma_kernel<<<(cnt_c + 31) / 32, 512, 0, stream>>>(
        nbr, lens, rels, adjw, feat, Wih, Whh, ord, phi, plo, s0, cnt_c);
    rgc_mfma_kernel<<<(cnt_c + 63) / 64, 256, 0, stream>>>(
        wt, phi, plo, nodes, ord, out, s0, cnt_c);
  }
  relu_kernel<<<(NS * OUTD / 4 + 255) / 256, 256, 0, stream>>>(
      (float4*)out, NS * OUTD / 4);
}

// Round 5
// 610.318 us; speedup vs baseline: 1.2674x; 1.2674x over previous
//
#include <hip/hip_runtime.h>

#define NS   50000
#define LSEQ 32
#define IND  64
#define HIDN 64
#define OUTD 128
#define NR   11

using bf16x8  = __attribute__((ext_vector_type(8))) short;
using f32x16  = __attribute__((ext_vector_type(16))) float;

union U8 { bf16x8 v; unsigned u[4]; uint2 d[2]; };

__device__ __forceinline__ unsigned cvt_pk_bf16(float a, float b) {
  unsigned r;
  asm volatile("v_cvt_pk_bf16_f32 %0, %1, %2" : "=v"(r) : "v"(a), "v"(b));
  return r;  // r[15:0] = bf16(a), r[31:16] = bf16(b)
}
__device__ __forceinline__ float fsig(float x) {
  return __builtin_amdgcn_rcpf(1.f + __expf(-x));
}
__device__ __forceinline__ float ftanh_(float x) {
  return 1.f - 2.f * __builtin_amdgcn_rcpf(__expf(2.f * x) + 1.f);
}
__device__ __forceinline__ void gload_lds16(const void* g, void* l) {
  __builtin_amdgcn_global_load_lds(
      (const __attribute__((address_space(1))) unsigned*)g,
      (__attribute__((address_space(3))) unsigned*)l, 16, 0, 0);
}

// ---------------- feature table -> bf16 (halves gather traffic) ------------
__global__ __launch_bounds__(256) void fprep_kernel(
    const float* __restrict__ f, unsigned* __restrict__ fb) {
  int i = blockIdx.x * 256 + threadIdx.x;      // uint index (2 floats)
  if (i < NS * IND / 2) {
    float2 v = ((const float2*)f)[i];
    fb[i] = cvt_pk_bf16(v.x, v.y);
  }
}

// ---------------- length sort (descending), LDS-binned ---------------------
__global__ void zero_cnt_kernel(int* cnt) {
  if (threadIdx.x < 64) cnt[threadIdx.x] = 0;  // cnt[32] + cur[32]
}
__global__ __launch_bounds__(256) void hist_kernel(
    const int* __restrict__ lens, int* __restrict__ cnt) {
  __shared__ int lc[32];
  int t = threadIdx.x;
  if (t < 32) lc[t] = 0;
  __syncthreads();
  int s = blockIdx.x * 256 + t;
  if (s < NS) atomicAdd(&lc[32 - lens[s]], 1);
  __syncthreads();
  if (t < 32 && lc[t]) atomicAdd(&cnt[t], lc[t]);
}
__global__ void prefix_kernel(const int* __restrict__ cnt, int* __restrict__ cur) {
  if (threadIdx.x == 0) {
    int sum = 0;
    for (int b = 0; b < 32; ++b) { cur[b] = sum; sum += cnt[b]; }
  }
}
__global__ __launch_bounds__(256) void scatter_kernel(
    const int* __restrict__ lens, int* __restrict__ cur, int* __restrict__ ord) {
  __shared__ int lc[32], lb[32];
  int t = threadIdx.x;
  if (t < 32) lc[t] = 0;
  __syncthreads();
  int s = blockIdx.x * 256 + t;
  int rank = 0, bin = 0;
  if (s < NS) {
    bin = 32 - lens[s];
    rank = atomicAdd(&lc[bin], 1);      // LDS atomic (fast)
  }
  __syncthreads();
  if (t < 32 && lc[t]) lb[t] = atomicAdd(&cur[t], lc[t]);  // 32/block global
  __syncthreads();
  if (s < NS) ord[lb[bin] + rank] = s;
}

// ---------------------------------------------------------------------------
// K1: fused gather + bf16-MFMA LSTM + relation pooling, length-sorted blocks.
// 512 thr / 8 waves / 32 samples; per-block steps = block-max length.
// bf16 feature gather (uint2/lane), 2-deep prefetch, 1 barrier/step,
// double-buffered XOR-swizzled activation tile.
// ---------------------------------------------------------------------------
__global__ __launch_bounds__(512, 4) void lstm_mfma_kernel(
    const unsigned* __restrict__ fb, const int* __restrict__ nbr,
    const int* __restrict__ lens, const int* __restrict__ rels,
    const float* __restrict__ adjw, const float* __restrict__ Wih,
    const float* __restrict__ Whh, const int* __restrict__ ord,
    unsigned* __restrict__ phi, unsigned* __restrict__ plo,
    int s0, int cnt)
{
  __shared__ short xh[2 * 32 * 128];   // 16KB: 2 x [32 samp][128 k] bf16, swizzled
  __shared__ float sh_w[32][33];
  __shared__ int   sh_meta[32][33];    // rel<<16 | nbr (nbr < 2^16)
  __shared__ int   sh_len[32];

  const int tid   = threadIdx.x;
  const int lane  = tid & 63;
  const int w     = tid >> 6;
  const int sbase = blockIdx.x * 32;

  for (int i = tid; i < 32 * 32; i += 512) {
    int ss = i >> 5, l = i & 31;
    int gp = sbase + ss;
    bool ok = gp < cnt;
    int gs = ok ? ord[s0 + gp] : 0;
    size_t off = (size_t)gs * LSEQ + l;
    sh_w[ss][l]    = ok ? adjw[off] : 0.f;
    sh_meta[ss][l] = ok ? ((rels[off] << 16) | nbr[off]) : 0;
  }
  if (tid < 32) {
    int gp = sbase + tid;
    sh_len[tid] = (gp < cnt) ? lens[ord[s0 + gp]] : 0;
  }
  for (int i = tid; i < 2 * 32 * 128; i += 512) xh[i] = 0;

  // stationary A fragments (gate-permuted weight rows, bf16)
  bf16x8 Af[8];
  {
    const int rr = lane & 31, kh = lane >> 5;
    const int g = rr & 3, q = rr >> 2;
    const int u = w * 8 + 4 * (q & 1) + (q >> 1);
    const int row = g * 64 + u;
#pragma unroll
    for (int kc = 0; kc < 8; ++kc) {
      int k0 = kc * 16 + kh * 8;
      const float* src = (k0 < 64) ? (Wih + row * 64 + k0)
                                   : (Whh + row * 64 + (k0 - 64));
      float4 f0 = *(const float4*)(src);
      float4 f1 = *(const float4*)(src + 4);
      U8 a;
      a.u[0] = cvt_pk_bf16(f0.x, f0.y); a.u[1] = cvt_pk_bf16(f0.z, f0.w);
      a.u[2] = cvt_pk_bf16(f1.x, f1.y); a.u[3] = cvt_pk_bf16(f1.z, f1.w);
      Af[kc] = a.v;
    }
  }

  const int s    = lane & 31;          // gate-phase sample
  const int hi   = lane >> 5;
  const int sxor = (s & 15) << 4;
  const int u0   = w * 8 + 4 * hi;     // 4 consecutive units
  const int hoff = s * 128 + (((128 + u0 * 2) ^ sxor) >> 1);   // short idx
  const int gsamp = tid >> 4, gseg = tid & 15;                 // gather role
  const int goff  = gsamp * 128 + (((gseg * 8) ^ ((gsamp & 15) << 4)) >> 1);

  float c4[4] = {0.f, 0.f, 0.f, 0.f};
  float pooled[4][NR] = {};

  __syncthreads();
  const int len_s = sh_len[s];
  const int len_g = sh_len[gsamp];
  const int tmax  = (sh_len[0] + 1) & ~1;   // block max (descending sort), even

  {  // prologue: x_0 -> buf0 (bf16 row, uint2 per lane)
    uint2 xv = make_uint2(0u, 0u);
    if (0 < len_g) {
      int nid = sh_meta[gsamp][0] & 0xffff;
      xv = *(const uint2*)(fb + (size_t)nid * 32 + gseg * 2);
    }
    *(uint2*)&xh[goff] = xv;
  }
  uint2 xA = make_uint2(0u, 0u), xB;
  if (1 < len_g) {
    int nid = sh_meta[gsamp][1] & 0xffff;
    xA = *(const uint2*)(fb + (size_t)nid * 32 + gseg * 2);
  }
  __syncthreads();

#define HALFSTEP(bufR, bufW, XLOAD, XWRITE, tc)                              \
  {                                                                          \
    uint2 xn = make_uint2(0u, 0u);                                           \
    if ((tc) + 2 < len_g) {                                                  \
      int nid = sh_meta[gsamp][(tc) + 2] & 0xffff;                           \
      xn = *(const uint2*)(fb + (size_t)nid * 32 + gseg * 2);                \
    }                                                                        \
    XLOAD = xn;                                                              \
    f32x16 acc = {};                                                         \
    _Pragma("unroll")                                                        \
    for (int kc = 0; kc < 8; ++kc) {                                         \
      int roff = s * 128 + (((kc * 32 + hi * 16) ^ sxor) >> 1);              \
      bf16x8 b = *(const bf16x8*)(&xh[(bufR) + roff]);                       \
      acc = __builtin_amdgcn_mfma_f32_32x32x16_bf16(Af[kc], b, acc, 0, 0, 0);\
    }                                                                        \
    int pk = sh_meta[s][tc];                                                 \
    float wv = ((tc) < len_s) ? sh_w[s][tc] : 0.f;                           \
    int rl = pk >> 16;                                                       \
    float h4[4];                                                             \
    _Pragma("unroll")                                                        \
    for (int p = 0; p < 4; ++p) {                                            \
      float gi = fsig(acc[4 * p + 0]);                                       \
      float gf = fsig(acc[4 * p + 1]);                                       \
      float gg = ftanh_(acc[4 * p + 2]);                                     \
      float go = fsig(acc[4 * p + 3]);                                       \
      float cc = gf * c4[p] + gi * gg;                                       \
      c4[p] = cc;                                                            \
      h4[p] = go * ftanh_(cc);                                               \
    }                                                                        \
    _Pragma("unroll")                                                        \
    for (int r = 0; r < NR; ++r) {                                           \
      float mr = (rl == r) ? wv : 0.f;                                       \
      pooled[0][r] += mr * h4[0]; pooled[1][r] += mr * h4[1];                \
      pooled[2][r] += mr * h4[2]; pooled[3][r] += mr * h4[3];                \
    }                                                                        \
    *(uint2*)&xh[(bufW) + hoff] = make_uint2(cvt_pk_bf16(h4[0], h4[1]),      \
                                             cvt_pk_bf16(h4[2], h4[3]));     \
    *(uint2*)&xh[(bufW) + goff] = XWRITE;                                    \
    __syncthreads();                                                         \
  }

#pragma unroll 1
  for (int t = 0; t < tmax; t += 2) {
    HALFSTEP(0,    4096, xB, xA, t)
    HALFSTEP(4096, 0,    xA, xB, t + 1)
  }
#undef HALFSTEP

  // pooled -> hi/lo bf16 planes: [sorted-pos][11][64] bf16 each
  if (sbase + s < cnt) {
    size_t base = ((size_t)(sbase + s) * NR) * 32;
#pragma unroll
    for (int r = 0; r < NR; ++r) {
      float p0 = pooled[0][r], p1 = pooled[1][r];
      float p2 = pooled[2][r], p3 = pooled[3][r];
      unsigned h0 = cvt_pk_bf16(p0, p1), h1 = cvt_pk_bf16(p2, p3);
      float l0 = p0 - __uint_as_float(h0 << 16);
      float l1 = p1 - __uint_as_float(h0 & 0xffff0000u);
      float l2 = p2 - __uint_as_float(h1 << 16);
      float l3 = p3 - __uint_as_float(h1 & 0xffff0000u);
      unsigned g0 = cvt_pk_bf16(l0, l1), g1 = cvt_pk_bf16(l2, l3);
      *(uint2*)&phi[base + r * 32 + (u0 >> 1)] = make_uint2(h0, h1);
      *(uint2*)&plo[base + r * 32 + (u0 >> 1)] = make_uint2(g0, g1);
    }
  }
}

// ---------------------------------------------------------------------------
// Prep: Wr[11][64][128] f32 -> wt[r]: [hi 16KB | lo 16KB], each [128 o][64 k]
// bf16 with baked 4-bit XOR swizzle (byte ^= (o&15)<<3) for conflict-free b64.
// ---------------------------------------------------------------------------
__global__ __launch_bounds__(256) void wprep_kernel(
    const float* __restrict__ Wr, unsigned* __restrict__ wt)
{
  __shared__ float wl[64 * 128];
  const int r = blockIdx.x;
  for (int i = threadIdx.x; i < 64 * 128; i += 256)
    wl[i] = Wr[r * 64 * 128 + i];
  __syncthreads();
  const int o = threadIdx.x >> 1, kb = (threadIdx.x & 1) * 32;
  const int sw = (o & 15) << 3;
  unsigned* hip = wt + r * 8192;
  unsigned* lop = hip + 4096;
  for (int k = kb; k < kb + 32; k += 2) {
    float f0 = wl[k * 128 + o], f1 = wl[(k + 1) * 128 + o];
    unsigned h = cvt_pk_bf16(f0, f1);
    float l0 = f0 - __uint_as_float(h << 16);
    float l1 = f1 - __uint_as_float(h & 0xffff0000u);
    unsigned l = cvt_pk_bf16(l0, l1);
    int byte = o * 128 + ((k * 2) ^ sw);
    hip[byte >> 2] = h;
    lop[byte >> 2] = l;
  }
}

// ---------------------------------------------------------------------------
// K2: proj = sum_r pooled_r @ W_r via split-bf16 MFMA (hi*hi + hi*lo + lo*hi),
// D[m=out][n=samp]; atomic scatter to out[nodes]. 256 thr / 4 waves / 64 samp.
// ---------------------------------------------------------------------------
__global__ __launch_bounds__(256, 4) void rgc_mfma_kernel(
    const unsigned* __restrict__ wt, const unsigned* __restrict__ phi,
    const unsigned* __restrict__ plo, const int* __restrict__ nodes,
    const int* __restrict__ ord, float* __restrict__ out, int s0, int cnt)
{
  __shared__ short wl[2 * 8192];   // 32KB: W hi | lo tile for current r
  const int tid = threadIdx.x, lane = tid & 63, nt = tid >> 6;
  const int l31 = lane & 31, lhi = lane >> 5;
  const int sbase = blockIdx.x * 64;

  const int row = nt * 32 + l31;            // wT row = out index
  const int rsw = (row & 15) << 3;
  int aoff[8];
#pragma unroll
  for (int kc = 0; kc < 4; ++kc)
#pragma unroll
    for (int hf = 0; hf < 2; ++hf)
      aoff[kc * 2 + hf] = row * 64 + (((kc * 32 + lhi * 16 + hf * 8) ^ rsw) >> 1);

  f32x16 acc0 = {}, acc1 = {};

  for (int r = 0; r < NR; ++r) {
    __syncthreads();
    {
      const char* src = (const char*)(wt + r * 8192);
#pragma unroll
      for (int i = 0; i < 8; ++i) {
        int off = (i * 4 + nt) * 1024 + lane * 16;
        gload_lds16(src + off, (char*)wl + off);
      }
    }
    __syncthreads();

    bf16x8 ahi[4], alo[4];
#pragma unroll
    for (int kc = 0; kc < 4; ++kc) {
      U8 a, b;
      a.d[0] = *(const uint2*)&wl[aoff[kc * 2 + 0]];
      a.d[1] = *(const uint2*)&wl[aoff[kc * 2 + 1]];
      b.d[0] = *(const uint2*)&wl[8192 + aoff[kc * 2 + 0]];
      b.d[1] = *(const uint2*)&wl[8192 + aoff[kc * 2 + 1]];
      ahi[kc] = a.v; alo[kc] = b.v;
    }

#pragma unroll
    for (int st = 0; st < 2; ++st) {
      f32x16& accr = st ? acc1 : acc0;
      int samp = sbase + st * 32 + l31;
      size_t bb = ((size_t)samp * NR + r) * 32 + lhi * 4;
#pragma unroll
      for (int kc = 0; kc < 4; ++kc) {
        U8 bh, bl;
        *(uint4*)bh.u = *(const uint4*)&phi[bb + kc * 8];
        *(uint4*)bl.u = *(const uint4*)&plo[bb + kc * 8];
        accr = __builtin_amdgcn_mfma_f32_32x32x16_bf16(ahi[kc], bh.v, accr, 0, 0, 0);
        accr = __builtin_amdgcn_mfma_f32_32x32x16_bf16(ahi[kc], bl.v, accr, 0, 0, 0);
        accr = __builtin_amdgcn_mfma_f32_32x32x16_bf16(alo[kc], bh.v, accr, 0, 0, 0);
      }
    }
  }

#pragma unroll
  for (int st = 0; st < 2; ++st) {
    int sl = sbase + st * 32 + l31;
    if (sl < cnt) {
      int nd = nodes[ord[s0 + sl]];
      float* dst = out + (size_t)nd * OUTD + nt * 32;
      const f32x16& a = st ? acc1 : acc0;
#pragma unroll
      for (int j = 0; j < 16; ++j) {
        int m = (j & 3) + 8 * (j >> 2) + 4 * lhi;
        atomicAdd(dst + m, a[j]);
      }
    }
  }
}

__global__ void relu_kernel(float4* __restrict__ out, int n4) {
  int i = blockIdx.x * 256 + threadIdx.x;
  if (i < n4) {
    float4 v = out[i];
    v.x = fmaxf(v.x, 0.f); v.y = fmaxf(v.y, 0.f);
    v.z = fmaxf(v.z, 0.f); v.w = fmaxf(v.w, 0.f);
    out[i] = v;
  }
}

extern "C" void kernel_launch(void* const* d_in, const int* in_sizes, int n_in,
                              void* d_out, int out_size, void* d_ws, size_t ws_size,
                              hipStream_t stream) {
  const int*   nbr   = (const int*)d_in[0];
  const int*   lens  = (const int*)d_in[1];
  const int*   rels  = (const int*)d_in[2];
  const int*   nodes = (const int*)d_in[3];
  const float* adjw  = (const float*)d_in[4];
  const float* feat  = (const float*)d_in[5];
  const float* Wih   = (const float*)d_in[6];
  const float* Whh   = (const float*)d_in[7];
  const float* Wr    = (const float*)d_in[8];
  float* out = (float*)d_out;

  hipMemsetAsync(d_out, 0, (size_t)NS * OUTD * sizeof(float), stream);

  // ws layout: wt [0,360448) | fb bf16 feat [360448, 6760448) |
  //            ord [6760448, 6960448) | cnt/cur [6960448, +256) | phi/plo
  unsigned* wt  = (unsigned*)d_ws;
  unsigned* fb  = (unsigned*)((char*)d_ws + 360448);
  int*      ord = (int*)((char*)d_ws + 6760448);
  int*      cnt = (int*)((char*)d_ws + 6960448);
  int*      cur = cnt + 32;
  const size_t PHI_OFF = 6960768;
  unsigned* phi = (unsigned*)((char*)d_ws + PHI_OFF);

  wprep_kernel<<<NR, 256, 0, stream>>>(Wr, wt);
  fprep_kernel<<<(NS * IND / 2 + 255) / 256, 256, 0, stream>>>(feat, fb);
  zero_cnt_kernel<<<1, 64, 0, stream>>>(cnt);
  hist_kernel<<<(NS + 255) / 256, 256, 0, stream>>>(lens, cnt);
  prefix_kernel<<<1, 64, 0, stream>>>(cnt, cur);
  scatter_kernel<<<(NS + 255) / 256, 256, 0, stream>>>(lens, cur, ord);

  size_t avail = (ws_size > PHI_OFF) ? ws_size - PHI_OFF : 0;
  long long cap = (long long)(avail / 2816);     // samples (1408B x 2 planes)
  long long ch = cap - 64;
  ch &= ~63LL;
  if (ch > NS) ch = NS;
  if (ch < 64) ch = 64;
  unsigned* plo = phi + (size_t)cap * 352;       // 352 u32 = 1408B per sample

  for (int s0 = 0; s0 < NS; s0 += (int)ch) {
    int cnt_c = (NS - s0 < (int)ch) ? (NS - s0) : (int)ch;
    lstm_mfma_kernel<<<(cnt_c + 31) / 32, 512, 0, stream>>>(
        fb, nbr, lens, rels, adjw, Wih, Whh, ord, phi, plo, s0, cnt_c);
    rgc_mfma_kernel<<<(cnt_c + 63) / 64, 256, 0, stream>>>(
        wt, phi, plo, nodes, ord, out, s0, cnt_c);
  }
  relu_kernel<<<(NS * OUTD / 4 + 255) / 256, 256, 0, stream>>>(
      (float4*)out, NS * OUTD / 4);
}